// Round 15
// baseline (181.310 us; speedup 1.0000x reference)
//
#include <hip/hip_runtime.h>
#include <math.h>

#define N_PTS 8192
#define KFULL 40
#define KNB 20
#define QB 8
#define KBLK 512
#define NBK 1024
#define CAP 512

typedef unsigned short u16;
typedef unsigned int u32;
typedef unsigned long long u64;
typedef __attribute__((ext_vector_type(8))) short bf16x8;
typedef __attribute__((ext_vector_type(4))) float f32x4;
typedef __attribute__((ext_vector_type(2))) float f32x2;

__device__ __forceinline__ u16 f2b(float v) {  // RNE float->bf16 bits
  u32 u = __float_as_uint(v);
  return (u16)((u + 0x7FFFu + ((u >> 16) & 1u)) >> 16);
}
__device__ __forceinline__ float b2f(u16 b) {
  return __uint_as_float(((u32)b) << 16);
}
__device__ __forceinline__ u32 pk2(float a, float b) {
  return (u32)f2b(a) | ((u32)f2b(b) << 16);
}
__device__ __forceinline__ u32 dmap(float d) {  // order-preserving float->u32
  u32 b = __float_as_uint(d);
  return b ^ ((u32)(((int)b) >> 31) | 0x80000000u);
}
__device__ __forceinline__ float inv_dmap(u32 m) {  // inverse of dmap
  return (m & 0x80000000u) ? __uint_as_float(m & 0x7FFFFFFFu)
                           : __uint_as_float(~m);
}
__device__ __forceinline__ float inv_edge(int b) {  // largest float in bucket b
  if (b >= 1022) return 3.4e38f;
  const u32 m = (((u32)(b + 1)) << 22) - 1u;
  if (m < 0x80000000u) return 0.f;
  return __uint_as_float(m - 0x80000000u);
}
__device__ __forceinline__ void maxu4(const uint4 v, float m[8]) {
  m[0] = fmaxf(m[0], __uint_as_float(v.x << 16));
  m[1] = fmaxf(m[1], __uint_as_float(v.x & 0xFFFF0000u));
  m[2] = fmaxf(m[2], __uint_as_float(v.y << 16));
  m[3] = fmaxf(m[3], __uint_as_float(v.y & 0xFFFF0000u));
  m[4] = fmaxf(m[4], __uint_as_float(v.z << 16));
  m[5] = fmaxf(m[5], __uint_as_float(v.z & 0xFFFF0000u));
  m[6] = fmaxf(m[6], __uint_as_float(v.w << 16));
  m[7] = fmaxf(m[7], __uint_as_float(v.w & 0xFFFF0000u));
}
__device__ __forceinline__ void unp4(const uint4 v, float p[8]) {
  p[0] = __uint_as_float(v.x << 16);
  p[1] = __uint_as_float(v.x & 0xFFFF0000u);
  p[2] = __uint_as_float(v.y << 16);
  p[3] = __uint_as_float(v.y & 0xFFFF0000u);
  p[4] = __uint_as_float(v.z << 16);
  p[5] = __uint_as_float(v.z & 0xFFFF0000u);
  p[6] = __uint_as_float(v.w << 16);
  p[7] = __uint_as_float(v.w & 0xFFFF0000u);
}

typedef const __attribute__((address_space(1))) unsigned int* gas_p;
typedef __attribute__((address_space(3))) unsigned int* las_p;
__device__ __forceinline__ void gll16(const void* g, void* l) {
  __builtin_amdgcn_global_load_lds((gas_p)g, (las_p)l, 16, 0, 0);
}

// packed distance for a query pair: d2 = qs2 + pw + qx2*px + qy2*py + qz2*pz
__device__ __forceinline__ f32x2 pdist(const f32x2 qx2, const f32x2 qy2,
                                       const f32x2 qz2, const f32x2 qs2,
                                       const float4 p) {
  const f32x2 px = {p.x, p.x}, py = {p.y, p.y}, pz = {p.z, p.z};
  const f32x2 pw = {p.w, p.w};
  return __builtin_elementwise_fma(
      qx2, px,
      __builtin_elementwise_fma(
          qy2, py, __builtin_elementwise_fma(qz2, pz, qs2 + pw)));
}

// wave-local cutoff scan over a plain u32 histogram (fallback path only)
__device__ __forceinline__ int scan_cut_wave(const u32* H, int lane) {
  const int base = lane * (NBK / 64);
  u32 lsum = 0;
#pragma unroll
  for (int k = 0; k < NBK / 64; ++k) lsum += H[base + k];
  u32 inc = lsum;
#pragma unroll
  for (int off = 1; off < 64; off <<= 1) {
    const u32 u = __shfl_up(inc, off);
    if (lane >= off) inc += u;
  }
  const u32 excl = inc - lsum;
  int cut = -1;
  if (excl < 41u && inc >= 41u) {
    u32 cum = excl;
    for (int k = 0; k < NBK / 64; ++k) {
      cum += H[base + k];
      if (cum >= 41u) { cut = base + k; break; }
    }
  }
  const u64 mask = __ballot(cut >= 0);
  if (mask == 0ull) return NBK - 1;
  const int src = __ffsll((long long)mask) - 1;
  return __shfl(cut, src);
}

// ---------------------------------------------------------------------------
// kNN v15 — near-LDS-free select (knn is LDS-op-throughput bound; R10/12/13
// nulls all explained by constant LDS-op count):
// Phase 0 (registers + ballot, ZERO LDS ops): wave w bounds its query's d_41.
//   Each lane keeps the 4 smallest dmap keys over its 32 stride-4 subsample
//   points; binary search (ballot+popcount) finds the EXACT 41st smallest of
//   the 256 kept keys. Any >=41-subset's 41st >= full 41st => certified bound,
//   no bucket inflation (cnt ~ 164 +- 26 << CAP).
// Single dense pass: compact d <= r2 into cand (1 atomic + 1 store/admit).
// Sort: fused register rank sort (4 keys, cmax<=256); multipass else.
// Fallback (cnt > CAP, ~never): exact wave-local redo (filtered histogram in
// own cand region -> refined bucket cutoff -> ballot compaction).
// Keys (dist | idx) reproduce top_k order; self = rank 0, dropped.
// ---------------------------------------------------------------------------
__global__ __launch_bounds__(KBLK) void knn_kernel(const float4* __restrict__ pos4,
                                                   int* __restrict__ idx_out) {
  __shared__ __align__(16) u64 candm[QB][CAP];  // 32 KB
  __shared__ float4 s_q[QB];
  __shared__ float s_r2[QB];
  __shared__ int s_cnt[QB];

  const int qb = blockIdx.x * QB, t = threadIdx.x;
  const int w = t >> 6, lane = t & 63;
  if (t < QB) {
    s_q[t] = pos4[qb + t];
    s_cnt[t] = 0;
  }
  __syncthreads();

  // ---- phase 0: register-resident bound for query w (no LDS traffic) ----
  {
    const float4 qv = s_q[w];
    const float ax = -2.0f * qv.x, ay = -2.0f * qv.y, az = -2.0f * qv.z;
    const float aw = qv.w;
    u32 k0 = ~0u, k1 = ~0u, k2 = ~0u, k3 = ~0u;  // 4 smallest, ascending
#pragma unroll 4
    for (int s = 0; s < 32; ++s) {
      const int j = (lane + (s << 6)) << 2;  // stride-4 subsample (2048 pts)
      const float4 p = pos4[j];
      const float d = fmaf(ax, p.x, fmaf(ay, p.y, fmaf(az, p.z, aw + p.w)));
      const u32 k = dmap(d);
      if (k < k3) {
        k3 = k;
        u32 tt;
        if (k3 < k2) { tt = k2; k2 = k3; k3 = tt; }
        if (k2 < k1) { tt = k1; k1 = k2; k2 = tt; }
        if (k1 < k0) { tt = k0; k0 = k1; k1 = tt; }
      }
    }
    // binary search: smallest v with |{kept keys <= v}| >= 41 (exact 41st)
    u32 lo = 0u, hi = ~0u;
    for (int it = 0; it < 32; ++it) {
      const u32 mid = lo + ((hi - lo) >> 1);
      const int c = __popcll(__ballot(k0 <= mid)) + __popcll(__ballot(k1 <= mid)) +
                    __popcll(__ballot(k2 <= mid)) + __popcll(__ballot(k3 <= mid));
      if (c >= (int)(KFULL + 1)) hi = mid; else lo = mid + 1;
    }
    if (lane == 0) s_r2[w] = inv_dmap(lo);
  }
  __syncthreads();

  f32x2 qx2[4], qy2[4], qz2[4], qs2[4];
  float r2[QB];
#pragma unroll
  for (int qp = 0; qp < 4; ++qp) {
    const float4 v0 = s_q[2 * qp], v1 = s_q[2 * qp + 1];
    qx2[qp] = (f32x2){-2.0f * v0.x, -2.0f * v1.x};
    qy2[qp] = (f32x2){-2.0f * v0.y, -2.0f * v1.y};
    qz2[qp] = (f32x2){-2.0f * v0.z, -2.0f * v1.z};
    qs2[qp] = (f32x2){v0.w, v1.w};
  }
#pragma unroll
  for (int q = 0; q < QB; ++q) r2[q] = s_r2[q];

  // ---- single dense pass: compact candidates (d <= r2) ----
#pragma unroll 2
  for (int s = 0; s < 16; ++s) {
    const int j = t + (s << 9);
    const float4 p = pos4[j];
#pragma unroll
    for (int qp = 0; qp < 4; ++qp) {
      const f32x2 d2 = pdist(qx2[qp], qy2[qp], qz2[qp], qs2[qp], p);
      if (d2.x <= r2[2 * qp]) {
        const int slot = atomicAdd(&s_cnt[2 * qp], 1);
        if (slot < CAP)
          candm[2 * qp][slot] = ((u64)dmap(d2.x) << 13) | (u64)j;
      }
      if (d2.y <= r2[2 * qp + 1]) {
        const int slot = atomicAdd(&s_cnt[2 * qp + 1], 1);
        if (slot < CAP)
          candm[2 * qp + 1][slot] = ((u64)dmap(d2.y) << 13) | (u64)j;
      }
    }
  }
  __syncthreads();

  // ---- per-wave: defensive exact fallback (~never) + rank sort ----
  {
    int cnt = s_cnt[w];
    if (cnt > CAP) {  // wave-uniform: redo this query exactly in own region
      const float4 qv = s_q[w];
      const float ax = -2.0f * qv.x, ay = -2.0f * qv.y, az = -2.0f * qv.z;
      const float aw = qv.w;
      const float R2w = s_r2[w];
      u32* fbh = (u32*)candm[w];  // own 4 KB region as u32 hist[1024]
      for (int b = lane; b < NBK; b += 64) fbh[b] = 0;
      for (int j = lane; j < N_PTS; j += 64) {
        const float4 p = pos4[j];
        const float d = fmaf(ax, p.x, fmaf(ay, p.y, fmaf(az, p.z, aw + p.w)));
        if (d <= R2w) atomicAdd(&fbh[dmap(d) >> 22], 1u);
      }
      const int cut2 = scan_cut_wave(fbh, lane);
      const float R2r = inv_edge(cut2);
      int base = 0;
      for (int j0 = 0; j0 < N_PTS; j0 += 64) {
        const int j = j0 + lane;
        const float4 p = pos4[j];
        const float d = fmaf(ax, p.x, fmaf(ay, p.y, fmaf(az, p.z, aw + p.w)));
        const bool pred = (d <= R2r);
        const u64 mask = __ballot(pred);
        if (pred) {
          const int off = __popcll(mask & ((1ull << lane) - 1ull));
          if (base + off < CAP)
            candm[w][base + off] = ((u64)dmap(d) << 13) | (u64)j;
        }
        base += (int)__popcll(mask);
      }
      cnt = base;
    }
    const int cmax = cnt < CAP ? cnt : CAP;
    if (cmax <= 256) {
      // fused rank sort: <=4 owned keys in registers, ONE broadcast pass
      const u64 FK = ~0ull;  // > any real key; never written (guarded)
      const u64 my0 = (lane < cmax) ? candm[w][lane] : FK;
      const u64 my1 = (lane + 64 < cmax) ? candm[w][lane + 64] : FK;
      const u64 my2 = (lane + 128 < cmax) ? candm[w][lane + 128] : FK;
      const u64 my3 = (lane + 192 < cmax) ? candm[w][lane + 192] : FK;
      int rk0 = 0, rk1 = 0, rk2 = 0, rk3 = 0;
      for (int c = 0; c < cmax; ++c) {
        const u64 bc = candm[w][c];  // same-address broadcast read
        rk0 += (bc < my0) ? 1 : 0;
        rk1 += (bc < my1) ? 1 : 0;
        rk2 += (bc < my2) ? 1 : 0;
        rk3 += (bc < my3) ? 1 : 0;
      }
      if (lane < cmax && rk0 >= 1 && rk0 <= KFULL)
        idx_out[(qb + w) * KFULL + (rk0 - 1)] = (int)(my0 & 0x1FFFull);
      if (lane + 64 < cmax && rk1 >= 1 && rk1 <= KFULL)
        idx_out[(qb + w) * KFULL + (rk1 - 1)] = (int)(my1 & 0x1FFFull);
      if (lane + 128 < cmax && rk2 >= 1 && rk2 <= KFULL)
        idx_out[(qb + w) * KFULL + (rk2 - 1)] = (int)(my2 & 0x1FFFull);
      if (lane + 192 < cmax && rk3 >= 1 && rk3 <= KFULL)
        idx_out[(qb + w) * KFULL + (rk3 - 1)] = (int)(my3 & 0x1FFFull);
    } else {
      for (int c0 = lane; c0 < cmax; c0 += 64) {
        const u64 my = candm[w][c0];
        int rank = 0;
        for (int c = 0; c < cmax; ++c) rank += (candm[w][c] < my) ? 1 : 0;
        if (rank >= 1 && rank <= KFULL)
          idx_out[(qb + w) * KFULL + (rank - 1)] = (int)(my & 0x1FFFull);
      }
    }
  }
}

// ---------------------------------------------------------------------------
// Weight convert+transpose body
// ---------------------------------------------------------------------------
__device__ __forceinline__ void wcvt_body(const float* __restrict__ src,
                                          u16* __restrict__ dst, int ncols,
                                          int rows_per_tensor, int elems_per_tensor,
                                          int rg, int k) {
  const int li = rg / rows_per_tensor;
  const int r = rg % rows_per_tensor;
  const float* s = src + (size_t)li * elems_per_tensor;
  u16* d = dst + (size_t)li * elems_per_tensor;
  const int part = r / ncols, col = r % ncols;
  d[(size_t)r * 128 + k] = f2b(s[(size_t)(part * 128 + k) * ncols + col]);
}

// ---------------------------------------------------------------------------
// Fused preamble: lift | Wg cvt | Wu cvt | Wr1 cvt | pos4.
// ---------------------------------------------------------------------------
__global__ __launch_bounds__(128) void prep_kernel(
    const float* __restrict__ x, const float* __restrict__ W0,
    const float* __restrict__ b0, const float* __restrict__ Wg,
    const float* __restrict__ Wu, const float* __restrict__ Wr1,
    float* __restrict__ Aout, u16* __restrict__ Pout, u16* __restrict__ Wgb,
    u16* __restrict__ Wub, u16* __restrict__ Wr1b, float4* __restrict__ pos4) {
  const int b = blockIdx.x, t = threadIdx.x;
  if (b < 8192) {  // lift: A = x@W0[0:3]+b0 (f32), P = x@W0[3:6] (bf16)
    const float px = x[b * 3 + 0], py = x[b * 3 + 1], pz = x[b * 3 + 2];
    const float a = b0[t] + px * W0[t] + py * W0[128 + t] + pz * W0[256 + t];
    const float p = px * W0[384 + t] + py * W0[512 + t] + pz * W0[640 + t];
    Aout[(size_t)b * 128 + t] = a;
    Pout[(size_t)b * 128 + t] = f2b(p);
  } else if (b < 9216) {
    wcvt_body(Wg, Wgb, 128, 256, 256 * 128, b - 8192, t);
  } else if (b < 10240) {
    wcvt_body(Wu, Wub, 512, 1024, 1024 * 128, b - 9216, t);
  } else if (b < 10368) {
    wcvt_body(Wr1, Wr1b, 128, 128, 128 * 128, b - 10240, t);
  } else {
    const int j = (b - 10368) * 128 + t;
    const float px = x[j * 3 + 0], py = x[j * 3 + 1], pz = x[j * 3 + 2];
    pos4[j] = make_float4(px, py, pz, px * px + py * py + pz * pz);
  }
}

// ---------------------------------------------------------------------------
// bf16 MFMA GEMM, K=128, BM=128, BN=64. Epilogue splits per-group cols into
// A (f32 or bf16 via Aout16, +bias, opt act) and P (bf16, no bias/act).
// ---------------------------------------------------------------------------
__global__ __launch_bounds__(256) void gemm_mfma_kernel(
    const u16* __restrict__ Ain, const u16* __restrict__ Wt,
    const float* __restrict__ bias, int GA, int span_shift, int nAtot, int nPtot,
    float slope, int use_act, float* __restrict__ Aout,
    u16* __restrict__ Aout16, u16* __restrict__ Pout) {
  __shared__ __align__(16) u16 Al[128 * 128];
  __shared__ __align__(16) u16 Bl[64 * 128];
  const int bm = blockIdx.x * 128;
  const int bn = blockIdx.y * 64;
  const int tid = threadIdx.x;

#pragma unroll
  for (int it = 0; it < 8; ++it) {
    const int g = it * 256 + tid;
    const int row = g >> 4, cc = g & 15;
    const int sc = cc ^ (row & 7);
    gll16(Ain + (size_t)(bm + row) * 128 + sc * 8, &Al[g * 8]);
  }
#pragma unroll
  for (int it = 0; it < 4; ++it) {
    const int g = it * 256 + tid;
    const int row = g >> 4, cc = g & 15;
    const int sc = cc ^ (row & 7);
    gll16(Wt + (size_t)(bn + row) * 128 + sc * 8, &Bl[g * 8]);
  }
  __syncthreads();

  const int wv = tid >> 6, lane = tid & 63;
  const int wm = wv & 1, wn = wv >> 1;
  const int lr = lane & 15, lk = lane >> 4;

  bf16x8 a[4][4], b[2][4];
  f32x4 acc[4][2];
#pragma unroll
  for (int m = 0; m < 4; ++m)
#pragma unroll
    for (int n = 0; n < 2; ++n) acc[m][n] = (f32x4){0.f, 0.f, 0.f, 0.f};

#pragma unroll
  for (int m = 0; m < 4; ++m) {
    const int row = wm * 64 + m * 16 + lr;
#pragma unroll
    for (int ks = 0; ks < 4; ++ks) {
      const int c = ks * 4 + lk;
      a[m][ks] = *(const bf16x8*)&Al[row * 128 + (c ^ (row & 7)) * 8];
    }
  }
#pragma unroll
  for (int n = 0; n < 2; ++n) {
    const int col = wn * 32 + n * 16 + lr;
#pragma unroll
    for (int ks = 0; ks < 4; ++ks) {
      const int c = ks * 4 + lk;
      b[n][ks] = *(const bf16x8*)&Bl[col * 128 + (c ^ (col & 7)) * 8];
    }
  }

#pragma unroll
  for (int ks = 0; ks < 4; ++ks)
#pragma unroll
    for (int m = 0; m < 4; ++m)
#pragma unroll
      for (int n = 0; n < 2; ++n)
        acc[m][n] = __builtin_amdgcn_mfma_f32_16x16x32_bf16(a[m][ks], b[n][ks],
                                                            acc[m][n], 0, 0, 0);

  const int span = 1 << span_shift;
  const int GP = span - GA;
#pragma unroll
  for (int n = 0; n < 2; ++n) {
    const int col = bn + wn * 32 + n * 16 + lr;
    const int g = col >> span_shift;
    const int wi = col & (span - 1);
    const bool isA = wi < GA;
    const float bv = isA ? bias[g * GA + wi] : 0.f;
#pragma unroll
    for (int m = 0; m < 4; ++m) {
      const int row0 = bm + wm * 64 + m * 16 + lk * 4;
#pragma unroll
      for (int r = 0; r < 4; ++r) {
        float v = acc[m][n][r] + bv;
        if (isA) {
          if (use_act) v = v > 0.f ? v : v * slope;
          if (Aout16)
            Aout16[(size_t)(row0 + r) * nAtot + g * GA + wi] = f2b(v);
          else
            Aout[(size_t)(row0 + r) * nAtot + g * GA + wi] = v;
        } else {
          Pout[(size_t)(row0 + r) * nPtot + g * GP + (wi - GA)] = f2b(v);
        }
      }
    }
  }
}

// ---------------------------------------------------------------------------
// Single-branch gather-max (first layer): out = LR(A - P_self + max_j P[nbr]).
// ---------------------------------------------------------------------------
__global__ __launch_bounds__(256) void gather_one_kernel(
    const float* __restrict__ A, const u16* __restrict__ P,
    const int* __restrict__ idx, int C, int dil, float* __restrict__ outf,
    u16* __restrict__ outb) {
  const int t = threadIdx.x;
  const int i = blockIdx.x * 16 + (t >> 4);
  const int c = blockIdx.y * 128 + (t & 15) * 8;
  float m[8];
#pragma unroll
  for (int k = 0; k < 8; ++k) m[k] = -INFINITY;
  const int ib = i * KFULL;
#pragma unroll
  for (int j = 0; j < KNB; ++j) {
    const int n = idx[ib + j * dil] & (N_PTS - 1);
    maxu4(*(const uint4*)&P[(size_t)n * C + c], m);
  }
  float pv[8];
  unp4(*(const uint4*)&P[(size_t)i * C + c], pv);
  const float4 a0 = *(const float4*)&A[(size_t)i * C + c];
  const float4 a1 = *(const float4*)&A[(size_t)i * C + c + 4];
  const float av[8] = {a0.x, a0.y, a0.z, a0.w, a1.x, a1.y, a1.z, a1.w};
  float v[8];
#pragma unroll
  for (int k = 0; k < 8; ++k) {
    const float x = av[k] - pv[k] + m[k];
    v[k] = x > 0.f ? x : 0.2f * x;
  }
  if (outf) {
    *(float4*)&outf[(size_t)i * C + c] = make_float4(v[0], v[1], v[2], v[3]);
    *(float4*)&outf[(size_t)i * C + c + 4] = make_float4(v[4], v[5], v[6], v[7]);
  }
  if (outb) {
    uint4 pb = {pk2(v[0], v[1]), pk2(v[2], v[3]), pk2(v[4], v[5]), pk2(v[6], v[7])};
    *(uint4*)&outb[(size_t)i * C + c] = pb;
  }
}

// ---------------------------------------------------------------------------
// Fused inception pair: h += 0.5*(LR(A0-P0+max_dil1 P0) + LR(A1-P1+max_dil2 P1))
// ---------------------------------------------------------------------------
__global__ __launch_bounds__(256) void gather_pair_kernel(
    const float* __restrict__ Ap, const u16* __restrict__ Pp,
    const int* __restrict__ idx, float* __restrict__ h, u16* __restrict__ hb) {
  const int t = threadIdx.x;
  const int i = blockIdx.x * 16 + (t >> 4);
  const int c = (t & 15) * 8;
  float m1[8], m2[8];
#pragma unroll
  for (int k = 0; k < 8; ++k) { m1[k] = -INFINITY; m2[k] = -INFINITY; }
  const int ib = i * KFULL;
#pragma unroll
  for (int j = 0; j < KNB; ++j) {
    const int n1 = idx[ib + j] & (N_PTS - 1);
    maxu4(*(const uint4*)&Pp[(size_t)n1 * 256 + c], m1);
    const int n2 = idx[ib + 2 * j] & (N_PTS - 1);
    maxu4(*(const uint4*)&Pp[(size_t)n2 * 256 + 128 + c], m2);
  }
  float p0[8], p1[8];
  unp4(*(const uint4*)&Pp[(size_t)i * 256 + c], p0);
  unp4(*(const uint4*)&Pp[(size_t)i * 256 + 128 + c], p1);
  const float4 a00 = *(const float4*)&Ap[(size_t)i * 256 + c];
  const float4 a01 = *(const float4*)&Ap[(size_t)i * 256 + c + 4];
  const float4 a10 = *(const float4*)&Ap[(size_t)i * 256 + 128 + c];
  const float4 a11 = *(const float4*)&Ap[(size_t)i * 256 + 128 + c + 4];
  const float av0[8] = {a00.x, a00.y, a00.z, a00.w, a01.x, a01.y, a01.z, a01.w};
  const float av1[8] = {a10.x, a10.y, a10.z, a10.w, a11.x, a11.y, a11.z, a11.w};
  const float4 h0 = *(const float4*)&h[(size_t)i * 128 + c];
  const float4 h1 = *(const float4*)&h[(size_t)i * 128 + c + 4];
  const float hv[8] = {h0.x, h0.y, h0.z, h0.w, h1.x, h1.y, h1.z, h1.w};
  float v[8];
#pragma unroll
  for (int k = 0; k < 8; ++k) {
    float x1 = av0[k] - p0[k] + m1[k];
    x1 = x1 > 0.f ? x1 : 0.2f * x1;
    float x2 = av1[k] - p1[k] + m2[k];
    x2 = x2 > 0.f ? x2 : 0.2f * x2;
    v[k] = hv[k] + 0.5f * (x1 + x2);
  }
  *(float4*)&h[(size_t)i * 128 + c] = make_float4(v[0], v[1], v[2], v[3]);
  *(float4*)&h[(size_t)i * 128 + c + 4] = make_float4(v[4], v[5], v[6], v[7]);
  uint4 pb = {pk2(v[0], v[1]), pk2(v[2], v[3]), pk2(v[4], v[5]), pk2(v[6], v[7])};
  *(uint4*)&hb[(size_t)i * 128 + c] = pb;
}

// ---------------------------------------------------------------------------
// Fused reconstructor tail (R14, passed): gather-max -> MLP(128) -> 3D out.
// ---------------------------------------------------------------------------
__global__ __launch_bounds__(256) void recon_fused_kernel(
    const u16* __restrict__ Ab16, const u16* __restrict__ Pb16,
    const int* __restrict__ idx, const u16* __restrict__ Wr1b,
    const float* __restrict__ br1, const float* __restrict__ Wr2,
    const float* __restrict__ br2, float* __restrict__ out) {
  __shared__ __align__(16) u16 Al[128 * 128];   // 32 KB (A tile, swizzled)
  __shared__ __align__(16) u16 Bl[128 * 128];   // 32 KB (Wr1 tile, swizzled)
  __shared__ __align__(16) u16 Tt[128 * 132];   // 33 KB (T tile, padded)
  __shared__ float w2s[387];                    // Wr2 (384) + br2 (3)
  const int b = blockIdx.x, tid = threadIdx.x;
  const int pbase = b * 32;

#pragma unroll
  for (int it = 0; it < 8; ++it) {
    const int g = it * 256 + tid;
    const int row = g >> 4, cc = g & 15;
    const int sc = cc ^ (row & 7);
    gll16(Wr1b + (size_t)row * 128 + sc * 8, &Bl[g * 8]);
  }
  if (tid < 128) {
    w2s[tid] = Wr2[tid];
    w2s[tid + 128] = Wr2[tid + 128];
    w2s[tid + 256] = Wr2[tid + 256];
  }
  if (tid < 3) w2s[384 + tid] = br2[tid];

#pragma unroll
  for (int it = 0; it < 4; ++it) {
    const int tau = it * 256 + tid;   // 0..1023
    const int rr = tau >> 3;          // 0..127
    const int cg = tau & 7;           // 0..7
    const int pl = rr >> 2, s = rr & 3;
    const int p = pbase + pl;
    const int colb = s * 128 + cg * 16;
    float m[8], m2[8];
#pragma unroll
    for (int k = 0; k < 8; ++k) { m[k] = -INFINITY; m2[k] = -INFINITY; }
    const int ib = p * KFULL;
#pragma unroll
    for (int j = 0; j < KNB; ++j) {
      const int n = idx[ib + j] & (N_PTS - 1);
      maxu4(*(const uint4*)&Pb16[(size_t)n * 512 + colb], m);
      maxu4(*(const uint4*)&Pb16[(size_t)n * 512 + colb + 8], m2);
    }
    float av[8], av2[8], pv[8], pv2[8];
    unp4(*(const uint4*)&Ab16[(size_t)p * 512 + colb], av);
    unp4(*(const uint4*)&Ab16[(size_t)p * 512 + colb + 8], av2);
    unp4(*(const uint4*)&Pb16[(size_t)p * 512 + colb], pv);
    unp4(*(const uint4*)&Pb16[(size_t)p * 512 + colb + 8], pv2);
    float v[8], v2[8];
#pragma unroll
    for (int k = 0; k < 8; ++k) {
      float x = av[k] - pv[k] + m[k];
      v[k] = x > 0.f ? x : 0.2f * x;
      float y = av2[k] - pv2[k] + m2[k];
      v2[k] = y > 0.f ? y : 0.2f * y;
    }
    uint4 w0 = {pk2(v[0], v[1]), pk2(v[2], v[3]), pk2(v[4], v[5]), pk2(v[6], v[7])};
    uint4 w1 = {pk2(v2[0], v2[1]), pk2(v2[2], v2[3]), pk2(v2[4], v2[5]),
                pk2(v2[6], v2[7])};
    const int c0 = cg * 2, c1 = cg * 2 + 1;
    *(uint4*)&Al[rr * 128 + (c0 ^ (rr & 7)) * 8] = w0;
    *(uint4*)&Al[rr * 128 + (c1 ^ (rr & 7)) * 8] = w1;
  }
  __syncthreads();

  const int wv = tid >> 6, lane = tid & 63;
  const int wm = wv & 1, wn = wv >> 1;
  const int lr = lane & 15, lk = lane >> 4;
  f32x4 acc[4][4];
#pragma unroll
  for (int m = 0; m < 4; ++m)
#pragma unroll
    for (int n = 0; n < 4; ++n) acc[m][n] = (f32x4){0.f, 0.f, 0.f, 0.f};

#pragma unroll
  for (int ks = 0; ks < 4; ++ks) {
    const int c = ks * 4 + lk;
    bf16x8 a[4], bb[4];
#pragma unroll
    for (int m = 0; m < 4; ++m) {
      const int row = wm * 64 + m * 16 + lr;
      a[m] = *(const bf16x8*)&Al[row * 128 + (c ^ (row & 7)) * 8];
    }
#pragma unroll
    for (int n = 0; n < 4; ++n) {
      const int col = wn * 64 + n * 16 + lr;
      bb[n] = *(const bf16x8*)&Bl[col * 128 + (c ^ (col & 7)) * 8];
    }
#pragma unroll
    for (int m = 0; m < 4; ++m)
#pragma unroll
      for (int n = 0; n < 4; ++n)
        acc[m][n] = __builtin_amdgcn_mfma_f32_16x16x32_bf16(a[m], bb[n],
                                                            acc[m][n], 0, 0, 0);
  }

#pragma unroll
  for (int n = 0; n < 4; ++n) {
    const int col = wn * 64 + n * 16 + lr;
    const float bv = br1[col];
#pragma unroll
    for (int m = 0; m < 4; ++m) {
      const int row0 = wm * 64 + m * 16 + lk * 4;
#pragma unroll
      for (int r = 0; r < 4; ++r) {
        float v = acc[m][n][r] + bv;
        v = v > 0.f ? v : 0.01f * v;
        Tt[(row0 + r) * 132 + col] = f2b(v);
      }
    }
  }
  __syncthreads();

  if (tid < 128) {
    float q0 = w2s[384], q1 = w2s[385], q2 = w2s[386];
#pragma unroll 4
    for (int k = 0; k < 128; ++k) {
      const float tv = b2f(Tt[tid * 132 + k]);
      q0 = fmaf(tv, w2s[k * 3 + 0], q0);
      q1 = fmaf(tv, w2s[k * 3 + 1], q1);
      q2 = fmaf(tv, w2s[k * 3 + 2], q2);
    }
    const size_t R = (size_t)b * 128 + tid;
    out[R * 3 + 0] = q0;
    out[R * 3 + 1] = q1;
    out[R * 3 + 2] = q2;
  }
}

// ---------------------------------------------------------------------------
extern "C" void kernel_launch(void* const* d_in, const int* in_sizes, int n_in,
                              void* d_out, int out_size, void* d_ws, size_t ws_size,
                              hipStream_t stream) {
  const float* x = (const float*)d_in[0];
  const float* W0 = (const float*)d_in[1];
  const float* b0 = (const float*)d_in[2];
  const float* Wg = (const float*)d_in[3];
  const float* bg = (const float*)d_in[4];
  const float* Wu = (const float*)d_in[5];
  const float* bu = (const float*)d_in[6];
  const float* Wr1 = (const float*)d_in[7];
  const float* br1 = (const float*)d_in[8];
  const float* Wr2 = (const float*)d_in[9];
  const float* br2 = (const float*)d_in[10];
  float* out = (float*)d_out;

  char* w = (char*)d_ws;
  int* idx = (int*)(w + 0);               // 1,310,720
  float4* pos4 = (float4*)(w + 1310720);  // 131,072
  float* h = (float*)(w + 1441792);       // 4 MB
  u16* hb = (u16*)(w + 5636096);          // 2 MB
  float* Apair = (float*)(w + 7733248);   // 8 MB
  u16* Ppair = (u16*)(w + 16121856);      // 4 MB
  u16* Wgb = (u16*)(w + 20316160);        // 256 KB
  u16* Wub = (u16*)(w + 20578304);        // 256 KB
  u16* Wr1b = (u16*)(w + 20840448);       // 32 KB
  float* Abig = (float*)(w + 20873216);   // 16 MB region (lift A f32; later Ab16)
  u16* Ab16 = (u16*)(w + 20873216);       // upsampler A bf16 [8192][512] (8 MB)
  u16* Pbig = (u16*)(w + 37650432);       // 8 MB

  // fused preamble: lift | Wg cvt | Wu cvt | Wr1 cvt | pos4
  prep_kernel<<<10432, 128, 0, stream>>>(x, W0, b0, Wg, Wu, Wr1, Abig, Pbig, Wgb,
                                         Wub, Wr1b, pos4);

  knn_kernel<<<N_PTS / QB, KBLK, 0, stream>>>(pos4, idx);

  gather_one_kernel<<<dim3(512, 1), 256, 0, stream>>>(Abig, Pbig, idx, 128, 1, h, hb);

  // 2 inception blocks, each = one pair-GEMM (N=512) + one fused gather
  for (int blk = 0; blk < 2; ++blk) {
    const int li = blk * 2;
    gemm_mfma_kernel<<<dim3(64, 8), 256, 0, stream>>>(
        hb, Wgb + (size_t)li * 256 * 128, bg + li * 128, 128, 8, 256, 256, 0.f, 0,
        Apair, (u16*)nullptr, Ppair);
    gather_pair_kernel<<<512, 256, 0, stream>>>(Apair, Ppair, idx, h, hb);
  }

  // NodeShuffle upsampler (r*C = 512): emit A (bf16) and P (bf16)
  gemm_mfma_kernel<<<dim3(64, 16), 256, 0, stream>>>(hb, Wub, bu, 512, 10, 512, 512,
                                                     0.f, 0, (float*)nullptr, Ab16,
                                                     Pbig);

  // fused reconstructor tail: gather-max -> MLP(128) -> 3D out
  recon_fused_kernel<<<256, 256, 0, stream>>>(Ab16, Pbig, idx, Wr1b, br1, Wr2, br2,
                                              out);
}

// Round 16
// 159.434 us; speedup vs baseline: 1.1372x; 1.1372x over previous
//
#include <hip/hip_runtime.h>
#include <math.h>

#define N_PTS 8192
#define KFULL 40
#define KNB 20
#define QB 8
#define KBLK 512
#define NBK 1024
#define CAP 512

typedef unsigned short u16;
typedef unsigned int u32;
typedef unsigned long long u64;
typedef __attribute__((ext_vector_type(8))) short bf16x8;
typedef __attribute__((ext_vector_type(4))) float f32x4;
typedef __attribute__((ext_vector_type(2))) float f32x2;

__device__ __forceinline__ u16 f2b(float v) {  // RNE float->bf16 bits
  u32 u = __float_as_uint(v);
  return (u16)((u + 0x7FFFu + ((u >> 16) & 1u)) >> 16);
}
__device__ __forceinline__ float b2f(u16 b) {
  return __uint_as_float(((u32)b) << 16);
}
__device__ __forceinline__ u32 pk2(float a, float b) {
  return (u32)f2b(a) | ((u32)f2b(b) << 16);
}
__device__ __forceinline__ u32 dmap(float d) {  // order-preserving float->u32
  u32 b = __float_as_uint(d);
  return b ^ ((u32)(((int)b) >> 31) | 0x80000000u);
}
__device__ __forceinline__ float inv_edge(int b) {  // largest float in bucket b
  if (b >= 1022) return 3.4e38f;
  const u32 m = (((u32)(b + 1)) << 22) - 1u;
  if (m < 0x80000000u) return 0.f;
  return __uint_as_float(m - 0x80000000u);
}
__device__ __forceinline__ void maxu4(const uint4 v, float m[8]) {
  m[0] = fmaxf(m[0], __uint_as_float(v.x << 16));
  m[1] = fmaxf(m[1], __uint_as_float(v.x & 0xFFFF0000u));
  m[2] = fmaxf(m[2], __uint_as_float(v.y << 16));
  m[3] = fmaxf(m[3], __uint_as_float(v.y & 0xFFFF0000u));
  m[4] = fmaxf(m[4], __uint_as_float(v.z << 16));
  m[5] = fmaxf(m[5], __uint_as_float(v.z & 0xFFFF0000u));
  m[6] = fmaxf(m[6], __uint_as_float(v.w << 16));
  m[7] = fmaxf(m[7], __uint_as_float(v.w & 0xFFFF0000u));
}
__device__ __forceinline__ void unp4(const uint4 v, float p[8]) {
  p[0] = __uint_as_float(v.x << 16);
  p[1] = __uint_as_float(v.x & 0xFFFF0000u);
  p[2] = __uint_as_float(v.y << 16);
  p[3] = __uint_as_float(v.y & 0xFFFF0000u);
  p[4] = __uint_as_float(v.z << 16);
  p[5] = __uint_as_float(v.z & 0xFFFF0000u);
  p[6] = __uint_as_float(v.w << 16);
  p[7] = __uint_as_float(v.w & 0xFFFF0000u);
}

typedef const __attribute__((address_space(1))) unsigned int* gas_p;
typedef __attribute__((address_space(3))) unsigned int* las_p;
__device__ __forceinline__ void gll16(const void* g, void* l) {
  __builtin_amdgcn_global_load_lds((gas_p)g, (las_p)l, 16, 0, 0);
}

// packed distance for a query pair: d2 = qs2 + pw + qx2*px + qy2*py + qz2*pz
__device__ __forceinline__ f32x2 pdist(const f32x2 qx2, const f32x2 qy2,
                                       const f32x2 qz2, const f32x2 qs2,
                                       const float4 p) {
  const f32x2 px = {p.x, p.x}, py = {p.y, p.y}, pz = {p.z, p.z};
  const f32x2 pw = {p.w, p.w};
  return __builtin_elementwise_fma(
      qx2, px,
      __builtin_elementwise_fma(
          qy2, py, __builtin_elementwise_fma(qz2, pz, qs2 + pw)));
}

// ---------------------------------------------------------------------------
// scan over packed histograms: find bucket where cumulative (incl self) >= 41.
// ---------------------------------------------------------------------------
__device__ __forceinline__ void scan_cut(const u32 (*hist)[NBK], int* s_cut,
                                         int t) {
  const int w = t >> 6, lane = t & 63;
  if (w < QB / 2) {
    const u32* H = hist[w];
    const int base = lane * (NBK / 64);
    u32 lsum = 0;
#pragma unroll
    for (int k = 0; k < NBK / 64; ++k) lsum += H[base + k];
    u32 inc = lsum;  // packed scan: halves < 2^15, no carry crossover
#pragma unroll
    for (int off = 1; off < 64; off <<= 1) {
      const u32 u = __shfl_up(inc, off);
      if (lane >= off) inc += u;
    }
    const u32 excl = inc - lsum;
    const u32 TGT = KFULL + 1;  // 41 incl. self
    const u32 exlo = excl & 0xFFFFu, inlo = inc & 0xFFFFu;
    if (exlo < TGT && inlo >= TGT) {
      u32 cum = exlo;
      for (int k = 0; k < NBK / 64; ++k) {
        cum += H[base + k] & 0xFFFFu;
        if (cum >= TGT) { s_cut[2 * w] = base + k; break; }
      }
    }
    const u32 exhi = excl >> 16, inhi = inc >> 16;
    if (exhi < TGT && inhi >= TGT) {
      u32 cum = exhi;
      for (int k = 0; k < NBK / 64; ++k) {
        cum += H[base + k] >> 16;
        if (cum >= TGT) { s_cut[2 * w + 1] = base + k; break; }
      }
    }
  }
}

// wave-local cutoff scan over a plain u32 histogram (fallback path)
__device__ __forceinline__ int scan_cut_wave(const u32* H, int lane) {
  const int base = lane * (NBK / 64);
  u32 lsum = 0;
#pragma unroll
  for (int k = 0; k < NBK / 64; ++k) lsum += H[base + k];
  u32 inc = lsum;
#pragma unroll
  for (int off = 1; off < 64; off <<= 1) {
    const u32 u = __shfl_up(inc, off);
    if (lane >= off) inc += u;
  }
  const u32 excl = inc - lsum;
  int cut = -1;
  if (excl < 41u && inc >= 41u) {
    u32 cum = excl;
    for (int k = 0; k < NBK / 64; ++k) {
      cum += H[base + k];
      if (cum >= 41u) { cut = base + k; break; }
    }
  }
  const u64 mask = __ballot(cut >= 0);
  if (mask == 0ull) return NBK - 1;
  const int src = __ffsll((long long)mask) - 1;
  return __shfl(cut, src);
}

// ---------------------------------------------------------------------------
// kNN (R13/R14, passed twice @ ~64 us): three-stage histogram select,
// packed-fp32 distances, fused register rank sort, exact overflow fallback.
// ---------------------------------------------------------------------------
__global__ __launch_bounds__(KBLK) void knn_kernel(const float4* __restrict__ pos4,
                                                   int* __restrict__ idx_out) {
  __shared__ __align__(16) u32 hmem[2 * QB * CAP];  // 32 KB: hist(16KB) / cand
  u32 (*hist)[NBK] = (u32(*)[NBK])hmem;             // 4 packed arrays x 1024
  u64 (*cand)[CAP] = (u64(*)[CAP])hmem;             // 8 x 512 u64
  __shared__ float4 s_q[QB];
  __shared__ int s_cut[QB];
  __shared__ int s_cnt[QB];

  const int qb = blockIdx.x * QB, t = threadIdx.x;
  if (t < QB) {
    s_q[t] = pos4[qb + t];
    s_cnt[t] = 0;
  }
  for (int b = t; b < 4 * NBK; b += KBLK) hmem[b] = 0;
  __syncthreads();

  f32x2 qx2[4], qy2[4], qz2[4], qs2[4];
#pragma unroll
  for (int qp = 0; qp < 4; ++qp) {
    const float4 v0 = s_q[2 * qp], v1 = s_q[2 * qp + 1];
    qx2[qp] = (f32x2){-2.0f * v0.x, -2.0f * v1.x};
    qy2[qp] = (f32x2){-2.0f * v0.y, -2.0f * v1.y};
    qz2[qp] = (f32x2){-2.0f * v0.z, -2.0f * v1.z};
    qs2[qp] = (f32x2){v0.w, v1.w};
  }

  // ---- phase 0: stride-16 subsample (512 pts, one per thread) ----
  {
    const int j = t << 4;
    const float4 p = pos4[j];
#pragma unroll
    for (int qp = 0; qp < 4; ++qp) {
      const f32x2 d2 = pdist(qx2[qp], qy2[qp], qz2[qp], qs2[qp], p);
      atomicAdd(&hist[qp][dmap(d2.x) >> 22], 1u);
      atomicAdd(&hist[qp][dmap(d2.y) >> 22], 0x10000u);
    }
  }
  __syncthreads();
  scan_cut(hist, s_cut, t);
  __syncthreads();
  float r2a[QB];
#pragma unroll
  for (int q = 0; q < QB; ++q) r2a[q] = inv_edge(s_cut[q]);
  for (int b = t; b < 4 * NBK; b += KBLK) hmem[b] = 0;
  __syncthreads();

  // ---- pass 1: filtered histogram ----
#pragma unroll 2
  for (int s = 0; s < 16; ++s) {
    const int j = t + (s << 9);
    const float4 p = pos4[j];
#pragma unroll
    for (int qp = 0; qp < 4; ++qp) {
      const f32x2 d2 = pdist(qx2[qp], qy2[qp], qz2[qp], qs2[qp], p);
      if (d2.x <= r2a[2 * qp]) atomicAdd(&hist[qp][dmap(d2.x) >> 22], 1u);
      if (d2.y <= r2a[2 * qp + 1]) atomicAdd(&hist[qp][dmap(d2.y) >> 22], 0x10000u);
    }
  }
  __syncthreads();
  scan_cut(hist, s_cut, t);
  __syncthreads();
  float r2b[QB];
#pragma unroll
  for (int q = 0; q < QB; ++q) r2b[q] = inv_edge(s_cut[q]);

  // ---- pass 2: compact candidates ----
#pragma unroll 2
  for (int s = 0; s < 16; ++s) {
    const int j = t + (s << 9);
    const float4 p = pos4[j];
#pragma unroll
    for (int qp = 0; qp < 4; ++qp) {
      const f32x2 d2 = pdist(qx2[qp], qy2[qp], qz2[qp], qs2[qp], p);
      if (d2.x <= r2b[2 * qp]) {
        const int slot = atomicAdd(&s_cnt[2 * qp], 1);
        if (slot < CAP)
          cand[2 * qp][slot] = ((u64)dmap(d2.x) << 13) | (u64)j;
      }
      if (d2.y <= r2b[2 * qp + 1]) {
        const int slot = atomicAdd(&s_cnt[2 * qp + 1], 1);
        if (slot < CAP)
          cand[2 * qp + 1][slot] = ((u64)dmap(d2.y) << 13) | (u64)j;
      }
    }
  }
  __syncthreads();

  // ---- per-wave: defensive exact fallback (~never) + rank sort ----
  {
    const int w = t >> 6, lane = t & 63;
    int cnt = s_cnt[w];
    if (cnt > CAP) {
      const float4 qv = s_q[w];
      const float ax = -2.0f * qv.x, ay = -2.0f * qv.y, az = -2.0f * qv.z;
      const float aw = qv.w;
      const float R2w = inv_edge(s_cut[w]);
      u32* fbh = (u32*)cand[w];
      for (int b = lane; b < NBK; b += 64) fbh[b] = 0;
      for (int j = lane; j < N_PTS; j += 64) {
        const float4 p = pos4[j];
        const float d = fmaf(ax, p.x, fmaf(ay, p.y, fmaf(az, p.z, aw + p.w)));
        if (d <= R2w) atomicAdd(&fbh[dmap(d) >> 22], 1u);
      }
      const int cut2 = scan_cut_wave(fbh, lane);
      const float R2r = inv_edge(cut2);
      int base = 0;
      for (int j0 = 0; j0 < N_PTS; j0 += 64) {
        const int j = j0 + lane;
        const float4 p = pos4[j];
        const float d = fmaf(ax, p.x, fmaf(ay, p.y, fmaf(az, p.z, aw + p.w)));
        const bool pred = (d <= R2r);
        const u64 mask = __ballot(pred);
        if (pred) {
          const int off = __popcll(mask & ((1ull << lane) - 1ull));
          if (base + off < CAP)
            cand[w][base + off] = ((u64)dmap(d) << 13) | (u64)j;
        }
        base += (int)__popcll(mask);
      }
      cnt = base;
    }
    const int cmax = cnt < CAP ? cnt : CAP;
    if (cmax <= 192) {
      const u64 FK = ~0ull;
      const u64 my0 = (lane < cmax) ? cand[w][lane] : FK;
      const u64 my1 = (lane + 64 < cmax) ? cand[w][lane + 64] : FK;
      const u64 my2 = (lane + 128 < cmax) ? cand[w][lane + 128] : FK;
      int rk0 = 0, rk1 = 0, rk2 = 0;
      for (int c = 0; c < cmax; ++c) {
        const u64 bc = cand[w][c];
        rk0 += (bc < my0) ? 1 : 0;
        rk1 += (bc < my1) ? 1 : 0;
        rk2 += (bc < my2) ? 1 : 0;
      }
      if (lane < cmax && rk0 >= 1 && rk0 <= KFULL)
        idx_out[(qb + w) * KFULL + (rk0 - 1)] = (int)(my0 & 0x1FFFull);
      if (lane + 64 < cmax && rk1 >= 1 && rk1 <= KFULL)
        idx_out[(qb + w) * KFULL + (rk1 - 1)] = (int)(my1 & 0x1FFFull);
      if (lane + 128 < cmax && rk2 >= 1 && rk2 <= KFULL)
        idx_out[(qb + w) * KFULL + (rk2 - 1)] = (int)(my2 & 0x1FFFull);
    } else {
      for (int c0 = lane; c0 < cmax; c0 += 64) {
        const u64 my = cand[w][c0];
        int rank = 0;
        for (int c = 0; c < cmax; ++c) rank += (cand[w][c] < my) ? 1 : 0;
        if (rank >= 1 && rank <= KFULL)
          idx_out[(qb + w) * KFULL + (rank - 1)] = (int)(my & 0x1FFFull);
      }
    }
  }
}

// ---------------------------------------------------------------------------
// Weight convert+transpose body
// ---------------------------------------------------------------------------
__device__ __forceinline__ void wcvt_body(const float* __restrict__ src,
                                          u16* __restrict__ dst, int ncols,
                                          int rows_per_tensor, int elems_per_tensor,
                                          int rg, int k) {
  const int li = rg / rows_per_tensor;
  const int r = rg % rows_per_tensor;
  const float* s = src + (size_t)li * elems_per_tensor;
  u16* d = dst + (size_t)li * elems_per_tensor;
  const int part = r / ncols, col = r % ncols;
  d[(size_t)r * 128 + k] = f2b(s[(size_t)(part * 128 + k) * ncols + col]);
}

// ---------------------------------------------------------------------------
// Fused preamble: lift | Wg cvt | Wu cvt | Wr1 cvt | pos4.
// ---------------------------------------------------------------------------
__global__ __launch_bounds__(128) void prep_kernel(
    const float* __restrict__ x, const float* __restrict__ W0,
    const float* __restrict__ b0, const float* __restrict__ Wg,
    const float* __restrict__ Wu, const float* __restrict__ Wr1,
    float* __restrict__ Aout, u16* __restrict__ Pout, u16* __restrict__ Wgb,
    u16* __restrict__ Wub, u16* __restrict__ Wr1b, float4* __restrict__ pos4) {
  const int b = blockIdx.x, t = threadIdx.x;
  if (b < 8192) {  // lift: A = x@W0[0:3]+b0 (f32), P = x@W0[3:6] (bf16)
    const float px = x[b * 3 + 0], py = x[b * 3 + 1], pz = x[b * 3 + 2];
    const float a = b0[t] + px * W0[t] + py * W0[128 + t] + pz * W0[256 + t];
    const float p = px * W0[384 + t] + py * W0[512 + t] + pz * W0[640 + t];
    Aout[(size_t)b * 128 + t] = a;
    Pout[(size_t)b * 128 + t] = f2b(p);
  } else if (b < 9216) {
    wcvt_body(Wg, Wgb, 128, 256, 256 * 128, b - 8192, t);
  } else if (b < 10240) {
    wcvt_body(Wu, Wub, 512, 1024, 1024 * 128, b - 9216, t);
  } else if (b < 10368) {
    wcvt_body(Wr1, Wr1b, 128, 128, 128 * 128, b - 10240, t);
  } else {
    const int j = (b - 10368) * 128 + t;
    const float px = x[j * 3 + 0], py = x[j * 3 + 1], pz = x[j * 3 + 2];
    pos4[j] = make_float4(px, py, pz, px * px + py * py + pz * pz);
  }
}

// ---------------------------------------------------------------------------
// bf16 MFMA GEMM, K=128, BM=128, BN=64. Epilogue splits per-group cols into
// A (f32 or bf16 via Aout16, +bias, opt act) and P (bf16, no bias/act).
// ---------------------------------------------------------------------------
__global__ __launch_bounds__(256) void gemm_mfma_kernel(
    const u16* __restrict__ Ain, const u16* __restrict__ Wt,
    const float* __restrict__ bias, int GA, int span_shift, int nAtot, int nPtot,
    float slope, int use_act, float* __restrict__ Aout,
    u16* __restrict__ Aout16, u16* __restrict__ Pout) {
  __shared__ __align__(16) u16 Al[128 * 128];
  __shared__ __align__(16) u16 Bl[64 * 128];
  const int bm = blockIdx.x * 128;
  const int bn = blockIdx.y * 64;
  const int tid = threadIdx.x;

#pragma unroll
  for (int it = 0; it < 8; ++it) {
    const int g = it * 256 + tid;
    const int row = g >> 4, cc = g & 15;
    const int sc = cc ^ (row & 7);
    gll16(Ain + (size_t)(bm + row) * 128 + sc * 8, &Al[g * 8]);
  }
#pragma unroll
  for (int it = 0; it < 4; ++it) {
    const int g = it * 256 + tid;
    const int row = g >> 4, cc = g & 15;
    const int sc = cc ^ (row & 7);
    gll16(Wt + (size_t)(bn + row) * 128 + sc * 8, &Bl[g * 8]);
  }
  __syncthreads();

  const int wv = tid >> 6, lane = tid & 63;
  const int wm = wv & 1, wn = wv >> 1;
  const int lr = lane & 15, lk = lane >> 4;

  bf16x8 a[4][4], b[2][4];
  f32x4 acc[4][2];
#pragma unroll
  for (int m = 0; m < 4; ++m)
#pragma unroll
    for (int n = 0; n < 2; ++n) acc[m][n] = (f32x4){0.f, 0.f, 0.f, 0.f};

#pragma unroll
  for (int m = 0; m < 4; ++m) {
    const int row = wm * 64 + m * 16 + lr;
#pragma unroll
    for (int ks = 0; ks < 4; ++ks) {
      const int c = ks * 4 + lk;
      a[m][ks] = *(const bf16x8*)&Al[row * 128 + (c ^ (row & 7)) * 8];
    }
  }
#pragma unroll
  for (int n = 0; n < 2; ++n) {
    const int col = wn * 32 + n * 16 + lr;
#pragma unroll
    for (int ks = 0; ks < 4; ++ks) {
      const int c = ks * 4 + lk;
      b[n][ks] = *(const bf16x8*)&Bl[col * 128 + (c ^ (col & 7)) * 8];
    }
  }

#pragma unroll
  for (int ks = 0; ks < 4; ++ks)
#pragma unroll
    for (int m = 0; m < 4; ++m)
#pragma unroll
      for (int n = 0; n < 2; ++n)
        acc[m][n] = __builtin_amdgcn_mfma_f32_16x16x32_bf16(a[m][ks], b[n][ks],
                                                            acc[m][n], 0, 0, 0);

  const int span = 1 << span_shift;
  const int GP = span - GA;
#pragma unroll
  for (int n = 0; n < 2; ++n) {
    const int col = bn + wn * 32 + n * 16 + lr;
    const int g = col >> span_shift;
    const int wi = col & (span - 1);
    const bool isA = wi < GA;
    const float bv = isA ? bias[g * GA + wi] : 0.f;
#pragma unroll
    for (int m = 0; m < 4; ++m) {
      const int row0 = bm + wm * 64 + m * 16 + lk * 4;
#pragma unroll
      for (int r = 0; r < 4; ++r) {
        float v = acc[m][n][r] + bv;
        if (isA) {
          if (use_act) v = v > 0.f ? v : v * slope;
          if (Aout16)
            Aout16[(size_t)(row0 + r) * nAtot + g * GA + wi] = f2b(v);
          else
            Aout[(size_t)(row0 + r) * nAtot + g * GA + wi] = v;
        } else {
          Pout[(size_t)(row0 + r) * nPtot + g * GP + (wi - GA)] = f2b(v);
        }
      }
    }
  }
}

// ---------------------------------------------------------------------------
// Single-branch gather-max: out = LR(A - P_self + max_j P[nbr_j], 0.2).
// idx rows staged in LDS once per block (16x redundant global loads removed).
// ---------------------------------------------------------------------------
__global__ __launch_bounds__(256) void gather_one_kernel(
    const float* __restrict__ A, const u16* __restrict__ P,
    const int* __restrict__ idx, int C, int dil, float* __restrict__ outf,
    u16* __restrict__ outb) {
  __shared__ int sidx[16 * KFULL];
  const int t = threadIdx.x;
  const int i0 = blockIdx.x * 16;
  for (int k = t; k < 16 * KFULL; k += 256) sidx[k] = idx[i0 * KFULL + k];
  __syncthreads();
  const int il = t >> 4;
  const int i = i0 + il;
  const int c = blockIdx.y * 128 + (t & 15) * 8;
  float m[8];
#pragma unroll
  for (int k = 0; k < 8; ++k) m[k] = -INFINITY;
  const int ib = il * KFULL;
#pragma unroll
  for (int j = 0; j < KNB; ++j) {
    const int n = sidx[ib + j * dil] & (N_PTS - 1);
    maxu4(*(const uint4*)&P[(size_t)n * C + c], m);
  }
  float pv[8];
  unp4(*(const uint4*)&P[(size_t)i * C + c], pv);
  const float4 a0 = *(const float4*)&A[(size_t)i * C + c];
  const float4 a1 = *(const float4*)&A[(size_t)i * C + c + 4];
  const float av[8] = {a0.x, a0.y, a0.z, a0.w, a1.x, a1.y, a1.z, a1.w};
  float v[8];
#pragma unroll
  for (int k = 0; k < 8; ++k) {
    const float x = av[k] - pv[k] + m[k];
    v[k] = x > 0.f ? x : 0.2f * x;
  }
  if (outf) {
    *(float4*)&outf[(size_t)i * C + c] = make_float4(v[0], v[1], v[2], v[3]);
    *(float4*)&outf[(size_t)i * C + c + 4] = make_float4(v[4], v[5], v[6], v[7]);
  }
  if (outb) {
    uint4 pb = {pk2(v[0], v[1]), pk2(v[2], v[3]), pk2(v[4], v[5]), pk2(v[6], v[7])};
    *(uint4*)&outb[(size_t)i * C + c] = pb;
  }
}

// ---------------------------------------------------------------------------
// Fused inception pair: h += 0.5*(LR(A0-P0+max_dil1 P0) + LR(A1-P1+max_dil2 P1))
// idx rows staged in LDS once per block.
// ---------------------------------------------------------------------------
__global__ __launch_bounds__(256) void gather_pair_kernel(
    const float* __restrict__ Ap, const u16* __restrict__ Pp,
    const int* __restrict__ idx, float* __restrict__ h, u16* __restrict__ hb) {
  __shared__ int sidx[16 * KFULL];
  const int t = threadIdx.x;
  const int i0 = blockIdx.x * 16;
  for (int k = t; k < 16 * KFULL; k += 256) sidx[k] = idx[i0 * KFULL + k];
  __syncthreads();
  const int il = t >> 4;
  const int i = i0 + il;
  const int c = (t & 15) * 8;
  float m1[8], m2[8];
#pragma unroll
  for (int k = 0; k < 8; ++k) { m1[k] = -INFINITY; m2[k] = -INFINITY; }
  const int ib = il * KFULL;
#pragma unroll
  for (int j = 0; j < KNB; ++j) {
    const int n1 = sidx[ib + j] & (N_PTS - 1);
    maxu4(*(const uint4*)&Pp[(size_t)n1 * 256 + c], m1);
    const int n2 = sidx[ib + 2 * j] & (N_PTS - 1);
    maxu4(*(const uint4*)&Pp[(size_t)n2 * 256 + 128 + c], m2);
  }
  float p0[8], p1[8];
  unp4(*(const uint4*)&Pp[(size_t)i * 256 + c], p0);
  unp4(*(const uint4*)&Pp[(size_t)i * 256 + 128 + c], p1);
  const float4 a00 = *(const float4*)&Ap[(size_t)i * 256 + c];
  const float4 a01 = *(const float4*)&Ap[(size_t)i * 256 + c + 4];
  const float4 a10 = *(const float4*)&Ap[(size_t)i * 256 + 128 + c];
  const float4 a11 = *(const float4*)&Ap[(size_t)i * 256 + 128 + c + 4];
  const float av0[8] = {a00.x, a00.y, a00.z, a00.w, a01.x, a01.y, a01.z, a01.w};
  const float av1[8] = {a10.x, a10.y, a10.z, a10.w, a11.x, a11.y, a11.z, a11.w};
  const float4 h0 = *(const float4*)&h[(size_t)i * 128 + c];
  const float4 h1 = *(const float4*)&h[(size_t)i * 128 + c + 4];
  const float hv[8] = {h0.x, h0.y, h0.z, h0.w, h1.x, h1.y, h1.z, h1.w};
  float v[8];
#pragma unroll
  for (int k = 0; k < 8; ++k) {
    float x1 = av0[k] - p0[k] + m1[k];
    x1 = x1 > 0.f ? x1 : 0.2f * x1;
    float x2 = av1[k] - p1[k] + m2[k];
    x2 = x2 > 0.f ? x2 : 0.2f * x2;
    v[k] = hv[k] + 0.5f * (x1 + x2);
  }
  *(float4*)&h[(size_t)i * 128 + c] = make_float4(v[0], v[1], v[2], v[3]);
  *(float4*)&h[(size_t)i * 128 + c + 4] = make_float4(v[4], v[5], v[6], v[7]);
  uint4 pb = {pk2(v[0], v[1]), pk2(v[2], v[3]), pk2(v[4], v[5]), pk2(v[6], v[7])};
  *(uint4*)&hb[(size_t)i * 128 + c] = pb;
}

// ---------------------------------------------------------------------------
// Fused reconstructor tail (R14, passed): gather-max -> MLP(128) -> 3D out.
// ---------------------------------------------------------------------------
__global__ __launch_bounds__(256) void recon_fused_kernel(
    const u16* __restrict__ Ab16, const u16* __restrict__ Pb16,
    const int* __restrict__ idx, const u16* __restrict__ Wr1b,
    const float* __restrict__ br1, const float* __restrict__ Wr2,
    const float* __restrict__ br2, float* __restrict__ out) {
  __shared__ __align__(16) u16 Al[128 * 128];   // 32 KB (A tile, swizzled)
  __shared__ __align__(16) u16 Bl[128 * 128];   // 32 KB (Wr1 tile, swizzled)
  __shared__ __align__(16) u16 Tt[128 * 132];   // 33 KB (T tile, padded)
  __shared__ float w2s[387];                    // Wr2 (384) + br2 (3)
  const int b = blockIdx.x, tid = threadIdx.x;
  const int pbase = b * 32;

#pragma unroll
  for (int it = 0; it < 8; ++it) {
    const int g = it * 256 + tid;
    const int row = g >> 4, cc = g & 15;
    const int sc = cc ^ (row & 7);
    gll16(Wr1b + (size_t)row * 128 + sc * 8, &Bl[g * 8]);
  }
  if (tid < 128) {
    w2s[tid] = Wr2[tid];
    w2s[tid + 128] = Wr2[tid + 128];
    w2s[tid + 256] = Wr2[tid + 256];
  }
  if (tid < 3) w2s[384 + tid] = br2[tid];

#pragma unroll
  for (int it = 0; it < 4; ++it) {
    const int tau = it * 256 + tid;   // 0..1023
    const int rr = tau >> 3;          // 0..127
    const int cg = tau & 7;           // 0..7
    const int pl = rr >> 2, s = rr & 3;
    const int p = pbase + pl;
    const int colb = s * 128 + cg * 16;
    float m[8], m2[8];
#pragma unroll
    for (int k = 0; k < 8; ++k) { m[k] = -INFINITY; m2[k] = -INFINITY; }
    const int ib = p * KFULL;
#pragma unroll
    for (int j = 0; j < KNB; ++j) {
      const int n = idx[ib + j] & (N_PTS - 1);
      maxu4(*(const uint4*)&Pb16[(size_t)n * 512 + colb], m);
      maxu4(*(const uint4*)&Pb16[(size_t)n * 512 + colb + 8], m2);
    }
    float av[8], av2[8], pv[8], pv2[8];
    unp4(*(const uint4*)&Ab16[(size_t)p * 512 + colb], av);
    unp4(*(const uint4*)&Ab16[(size_t)p * 512 + colb + 8], av2);
    unp4(*(const uint4*)&Pb16[(size_t)p * 512 + colb], pv);
    unp4(*(const uint4*)&Pb16[(size_t)p * 512 + colb + 8], pv2);
    float v[8], v2[8];
#pragma unroll
    for (int k = 0; k < 8; ++k) {
      float x = av[k] - pv[k] + m[k];
      v[k] = x > 0.f ? x : 0.2f * x;
      float y = av2[k] - pv2[k] + m2[k];
      v2[k] = y > 0.f ? y : 0.2f * y;
    }
    uint4 w0 = {pk2(v[0], v[1]), pk2(v[2], v[3]), pk2(v[4], v[5]), pk2(v[6], v[7])};
    uint4 w1 = {pk2(v2[0], v2[1]), pk2(v2[2], v2[3]), pk2(v2[4], v2[5]),
                pk2(v2[6], v2[7])};
    const int c0 = cg * 2, c1 = cg * 2 + 1;
    *(uint4*)&Al[rr * 128 + (c0 ^ (rr & 7)) * 8] = w0;
    *(uint4*)&Al[rr * 128 + (c1 ^ (rr & 7)) * 8] = w1;
  }
  __syncthreads();

  const int wv = tid >> 6, lane = tid & 63;
  const int wm = wv & 1, wn = wv >> 1;
  const int lr = lane & 15, lk = lane >> 4;
  f32x4 acc[4][4];
#pragma unroll
  for (int m = 0; m < 4; ++m)
#pragma unroll
    for (int n = 0; n < 4; ++n) acc[m][n] = (f32x4){0.f, 0.f, 0.f, 0.f};

#pragma unroll
  for (int ks = 0; ks < 4; ++ks) {
    const int c = ks * 4 + lk;
    bf16x8 a[4], bb[4];
#pragma unroll
    for (int m = 0; m < 4; ++m) {
      const int row = wm * 64 + m * 16 + lr;
      a[m] = *(const bf16x8*)&Al[row * 128 + (c ^ (row & 7)) * 8];
    }
#pragma unroll
    for (int n = 0; n < 4; ++n) {
      const int col = wn * 64 + n * 16 + lr;
      bb[n] = *(const bf16x8*)&Bl[col * 128 + (c ^ (col & 7)) * 8];
    }
#pragma unroll
    for (int m = 0; m < 4; ++m)
#pragma unroll
      for (int n = 0; n < 4; ++n)
        acc[m][n] = __builtin_amdgcn_mfma_f32_16x16x32_bf16(a[m], bb[n],
                                                            acc[m][n], 0, 0, 0);
  }

#pragma unroll
  for (int n = 0; n < 4; ++n) {
    const int col = wn * 64 + n * 16 + lr;
    const float bv = br1[col];
#pragma unroll
    for (int m = 0; m < 4; ++m) {
      const int row0 = wm * 64 + m * 16 + lk * 4;
#pragma unroll
      for (int r = 0; r < 4; ++r) {
        float v = acc[m][n][r] + bv;
        v = v > 0.f ? v : 0.01f * v;
        Tt[(row0 + r) * 132 + col] = f2b(v);
      }
    }
  }
  __syncthreads();

  if (tid < 128) {
    float q0 = w2s[384], q1 = w2s[385], q2 = w2s[386];
#pragma unroll 4
    for (int k = 0; k < 128; ++k) {
      const float tv = b2f(Tt[tid * 132 + k]);
      q0 = fmaf(tv, w2s[k * 3 + 0], q0);
      q1 = fmaf(tv, w2s[k * 3 + 1], q1);
      q2 = fmaf(tv, w2s[k * 3 + 2], q2);
    }
    const size_t R = (size_t)b * 128 + tid;
    out[R * 3 + 0] = q0;
    out[R * 3 + 1] = q1;
    out[R * 3 + 2] = q2;
  }
}

// ---------------------------------------------------------------------------
extern "C" void kernel_launch(void* const* d_in, const int* in_sizes, int n_in,
                              void* d_out, int out_size, void* d_ws, size_t ws_size,
                              hipStream_t stream) {
  const float* x = (const float*)d_in[0];
  const float* W0 = (const float*)d_in[1];
  const float* b0 = (const float*)d_in[2];
  const float* Wg = (const float*)d_in[3];
  const float* bg = (const float*)d_in[4];
  const float* Wu = (const float*)d_in[5];
  const float* bu = (const float*)d_in[6];
  const float* Wr1 = (const float*)d_in[7];
  const float* br1 = (const float*)d_in[8];
  const float* Wr2 = (const float*)d_in[9];
  const float* br2 = (const float*)d_in[10];
  float* out = (float*)d_out;

  char* w = (char*)d_ws;
  int* idx = (int*)(w + 0);               // 1,310,720
  float4* pos4 = (float4*)(w + 1310720);  // 131,072
  float* h = (float*)(w + 1441792);       // 4 MB
  u16* hb = (u16*)(w + 5636096);          // 2 MB
  float* Apair = (float*)(w + 7733248);   // 8 MB
  u16* Ppair = (u16*)(w + 16121856);      // 4 MB
  u16* Wgb = (u16*)(w + 20316160);        // 256 KB
  u16* Wub = (u16*)(w + 20578304);        // 256 KB
  u16* Wr1b = (u16*)(w + 20840448);       // 32 KB
  float* Abig = (float*)(w + 20873216);   // 16 MB region (lift A f32; later Ab16)
  u16* Ab16 = (u16*)(w + 20873216);       // upsampler A bf16 [8192][512] (8 MB)
  u16* Pbig = (u16*)(w + 37650432);       // 8 MB

  // fused preamble: lift | Wg cvt | Wu cvt | Wr1 cvt | pos4
  prep_kernel<<<10432, 128, 0, stream>>>(x, W0, b0, Wg, Wu, Wr1, Abig, Pbig, Wgb,
                                         Wub, Wr1b, pos4);

  knn_kernel<<<N_PTS / QB, KBLK, 0, stream>>>(pos4, idx);

  gather_one_kernel<<<dim3(512, 1), 256, 0, stream>>>(Abig, Pbig, idx, 128, 1, h, hb);

  // 2 inception blocks, each = one pair-GEMM (N=512) + one fused gather
  for (int blk = 0; blk < 2; ++blk) {
    const int li = blk * 2;
    gemm_mfma_kernel<<<dim3(64, 8), 256, 0, stream>>>(
        hb, Wgb + (size_t)li * 256 * 128, bg + li * 128, 128, 8, 256, 256, 0.f, 0,
        Apair, (u16*)nullptr, Ppair);
    gather_pair_kernel<<<512, 256, 0, stream>>>(Apair, Ppair, idx, h, hb);
  }

  // NodeShuffle upsampler (r*C = 512): emit A (bf16) and P (bf16)
  gemm_mfma_kernel<<<dim3(64, 16), 256, 0, stream>>>(hb, Wub, bu, 512, 10, 512, 512,
                                                     0.f, 0, (float*)nullptr, Ab16,
                                                     Pbig);

  // fused reconstructor tail: gather-max -> MLP(128) -> 3D out
  recon_fused_kernel<<<256, 256, 0, stream>>>(Ab16, Pbig, idx, Wr1b, br1, Wr2, br2,
                                              out);
}